// Round 8
// baseline (144.715 us; speedup 1.0000x reference)
//
#include <hip/hip_runtime.h>

#define H 4096
#define W 4096
#define ALPHA 0.2
#define NBLK 2048   // 2048 blocks * 32 KB/buffer = 64 MB = H*W floats

typedef float f4 __attribute__((ext_vector_type(4)));

__device__ __forceinline__ int reflect_idx(int i, int n) {
    if (i < 0) return -i;              // reflect-101, |offset| <= 1 here
    if (i >= n) return 2 * n - 2 - i;
    return i;
}

// Blocks 0..NBLK-1: masked-MSE partials. Each wave owns a contiguous 8 KB
// span of each buffer: lane*16B + k*1024B (k=0..7). 16 loads issued via one
// asm block (early-clobber outputs -> compiler CANNOT split the batch or
// share registers), single vmcnt(0) drain -> 16 outstanding loads/wave.
// Block NBLK: corner term for the analytically-collapsed conv branch.
// partial layout (floats): [2*b] = sum d^2, [2*b+1] = count, [2*NBLK] = y.
__global__ __launch_bounds__(256)
void mse_kernel(const float* __restrict__ pred,
                const float* __restrict__ target,
                float* __restrict__ partial) {
    const int bid = blockIdx.x;
    const int tid = threadIdx.x;

    if (bid < NBLK) {
        const int wave = tid >> 6, lane = tid & 63;
        const int region = bid * 32768 + wave * 8192 + lane * 16; // bytes
        const char* ta0 = (const char*)target + region;
        const char* ta1 = ta0 + 4096;
        const char* pa0 = (const char*)pred + region;
        const char* pa1 = pa0 + 4096;

        f4 t0, t1, t2, t3, t4, t5, t6, t7;
        f4 p0, p1, p2, p3, p4, p5, p6, p7;
        asm volatile(
            "global_load_dwordx4 %[t0], %[ta0], off\n\t"
            "global_load_dwordx4 %[t1], %[ta0], off offset:1024\n\t"
            "global_load_dwordx4 %[t2], %[ta0], off offset:2048\n\t"
            "global_load_dwordx4 %[t3], %[ta0], off offset:3072\n\t"
            "global_load_dwordx4 %[t4], %[ta1], off\n\t"
            "global_load_dwordx4 %[t5], %[ta1], off offset:1024\n\t"
            "global_load_dwordx4 %[t6], %[ta1], off offset:2048\n\t"
            "global_load_dwordx4 %[t7], %[ta1], off offset:3072\n\t"
            "global_load_dwordx4 %[p0], %[pa0], off\n\t"
            "global_load_dwordx4 %[p1], %[pa0], off offset:1024\n\t"
            "global_load_dwordx4 %[p2], %[pa0], off offset:2048\n\t"
            "global_load_dwordx4 %[p3], %[pa0], off offset:3072\n\t"
            "global_load_dwordx4 %[p4], %[pa1], off\n\t"
            "global_load_dwordx4 %[p5], %[pa1], off offset:1024\n\t"
            "global_load_dwordx4 %[p6], %[pa1], off offset:2048\n\t"
            "global_load_dwordx4 %[p7], %[pa1], off offset:3072\n\t"
            "s_waitcnt vmcnt(0)"
            : [t0]"=&v"(t0), [t1]"=&v"(t1), [t2]"=&v"(t2), [t3]"=&v"(t3),
              [t4]"=&v"(t4), [t5]"=&v"(t5), [t6]"=&v"(t6), [t7]"=&v"(t7),
              [p0]"=&v"(p0), [p1]"=&v"(p1), [p2]"=&v"(p2), [p3]"=&v"(p3),
              [p4]"=&v"(p4), [p5]"=&v"(p5), [p6]"=&v"(p6), [p7]"=&v"(p7)
            : [ta0]"v"(ta0), [ta1]"v"(ta1), [pa0]"v"(pa0), [pa1]"v"(pa1));

        float sA = 0.f, cA = 0.f, sB = 0.f, cB = 0.f;
#define CONSUME(tt, pp)                                        \
        {                                                      \
            float dx = tt.x - pp.x, dy = tt.y - pp.y;          \
            float dz = tt.z - pp.z, dw = tt.w - pp.w;          \
            if (tt.x > 0.f) { sA += dx * dx; cA += 1.f; }      \
            if (tt.y > 0.f) { sB += dy * dy; cB += 1.f; }      \
            if (tt.z > 0.f) { sA += dz * dz; cA += 1.f; }      \
            if (tt.w > 0.f) { sB += dw * dw; cB += 1.f; }      \
        }
        CONSUME(t0, p0) CONSUME(t1, p1) CONSUME(t2, p2) CONSUME(t3, p3)
        CONSUME(t4, p4) CONSUME(t5, p5) CONSUME(t6, p6) CONSUME(t7, p7)
#undef CONSUME

        float s = sA + sB, cnt = cA + cB;
        #pragma unroll
        for (int off = 32; off > 0; off >>= 1) {
            s   += __shfl_down(s, off);
            cnt += __shfl_down(cnt, off);
        }
        __shared__ float ws[4][2];
        if (lane == 0) { ws[wave][0] = s; ws[wave][1] = cnt; }
        __syncthreads();
        if (tid == 0) {
            partial[2 * bid]     = ws[0][0] + ws[1][0] + ws[2][0] + ws[3][0];
            partial[2 * bid + 1] = ws[0][1] + ws[1][1] + ws[2][1] + ws[3][1];
        }
    } else {
        // sum(G) = sum over r in {0,1,H-2,H-1} x c in {0,1,W-2,W-1} of
        // wr*wc*B(r,c); w=-1 at {0,1}, +1 at {n-2,n-1}; B = 3x3 gauss of t-p.
        float y = 0.f;
        if (tid < 16) {
            const int rows[4] = {0, 1, H - 2, H - 1};
            const int cols[4] = {0, 1, W - 2, W - 1};
            const float g[3] = {0.25f, 0.5f, 0.25f};
            const int ri = tid >> 2, ci = tid & 3;
            const int r = rows[ri], c = cols[ci];
            float b = 0.f;
            #pragma unroll
            for (int a = -1; a <= 1; ++a) {
                #pragma unroll
                for (int e = -1; e <= 1; ++e) {
                    int rr = reflect_idx(r + a, H);
                    int cc = reflect_idx(c + e, W);
                    b += g[a + 1] * g[e + 1] *
                         (target[rr * W + cc] - pred[rr * W + cc]);
                }
            }
            y = (((ri < 2) ? -1.f : 1.f) * ((ci < 2) ? -1.f : 1.f)) * b;
        }
        #pragma unroll
        for (int off = 8; off > 0; off >>= 1) y += __shfl_down(y, off);
        if (tid == 0) partial[2 * NBLK] = y;
    }
}

// One block: reduce NBLK (s,cnt) float2 partials + corner y -> scalar loss.
__global__ __launch_bounds__(256)
void finalize(const float* __restrict__ partial, float* __restrict__ out) {
    const int tid = threadIdx.x;
    const float2* p2 = (const float2*)partial;
    double s = 0.0, c = 0.0;
    #pragma unroll
    for (int j = 0; j < NBLK / 256; ++j) {
        float2 v = p2[tid + j * 256];
        s += (double)v.x;
        c += (double)v.y;
    }
    #pragma unroll
    for (int off = 32; off > 0; off >>= 1) {
        s += __shfl_down(s, off);
        c += __shfl_down(c, off);
    }
    __shared__ double ws[4][2];
    const int wave = tid >> 6, lane = tid & 63;
    if (lane == 0) { ws[wave][0] = s; ws[wave][1] = c; }
    __syncthreads();
    if (tid == 0) {
        double sd2 = ws[0][0] + ws[1][0] + ws[2][0] + ws[3][0];
        double cnt = ws[0][1] + ws[1][1] + ws[2][1] + ws[3][1];
        double mse = sd2 / fmax(cnt, 1.0);
        double meanG = (double)partial[2 * NBLK] / ((double)H * (double)W);
        out[0] = (float)(ALPHA * meanG + (1.0 - ALPHA) * mse);
    }
}

extern "C" void kernel_launch(void* const* d_in, const int* in_sizes, int n_in,
                              void* d_out, int out_size, void* d_ws, size_t ws_size,
                              hipStream_t stream) {
    const float* pred   = (const float*)d_in[0];
    const float* target = (const float*)d_in[1];
    float* out = (float*)d_out;
    float* partial = (float*)d_ws;   // (2*NBLK + 1) floats, all written every call

    mse_kernel<<<NBLK + 1, 256, 0, stream>>>(pred, target, partial);
    finalize<<<1, 256, 0, stream>>>(partial, out);
}

// Round 10
// 136.737 us; speedup vs baseline: 1.0583x; 1.0583x over previous
//
#include <hip/hip_runtime.h>

#define H 4096
#define W 4096
#define ALPHA 0.2
#define NBLK 2048
#define PT 8   // float4-pairs per thread: 2048 blk * 256 thr * 8 = 4M float4 = H*W floats

typedef float f4 __attribute__((ext_vector_type(4)));  // native clang vector:
// __builtin_nontemporal_load accepts it (HIP_vector_type float4 is rejected).

__device__ __forceinline__ int reflect_idx(int i, int n) {
    if (i < 0) return -i;              // reflect-101, |offset| <= 1 here
    if (i >= n) return 2 * n - 2 - i;
    return i;
}

// Blocks 0..NBLK-1: masked-MSE partials over a contiguous 32 KB span/buffer.
// Loads are NON-TEMPORAL (global_load_dwordx4 ... nt): no L1/L2 allocation.
// R3/R4/R5/R8 proved time is invariant to per-wave ILP depth (41-43 us across
// 4 schedules) -> limiter is the cache-allocating read path, not MLP.
// Block NBLK: corner term for the analytically-collapsed conv branch.
// partial layout (floats): [2*b] = sum d^2, [2*b+1] = count, [2*NBLK] = y.
__global__ __launch_bounds__(256)
void mse_kernel(const f4* __restrict__ pred,
                const f4* __restrict__ target,
                float* __restrict__ partial) {
    const int bid = blockIdx.x;
    const int tid = threadIdx.x;

    if (bid < NBLK) {
        const int base = bid * (256 * PT) + tid;
        f4 t[PT], p[PT];
        #pragma unroll
        for (int k = 0; k < PT; ++k) {
            t[k] = __builtin_nontemporal_load(&target[base + k * 256]);
            p[k] = __builtin_nontemporal_load(&pred[base + k * 256]);
        }

        float sA = 0.f, cA = 0.f, sB = 0.f, cB = 0.f;
        #pragma unroll
        for (int k = 0; k < PT; ++k) {
            f4 tt = t[k], pp = p[k];
            float dx = tt.x - pp.x, dy = tt.y - pp.y;
            float dz = tt.z - pp.z, dw = tt.w - pp.w;
            if (tt.x > 0.f) { sA += dx * dx; cA += 1.f; }
            if (tt.y > 0.f) { sB += dy * dy; cB += 1.f; }
            if (tt.z > 0.f) { sA += dz * dz; cA += 1.f; }
            if (tt.w > 0.f) { sB += dw * dw; cB += 1.f; }
        }
        float s = sA + sB, cnt = cA + cB;
        #pragma unroll
        for (int off = 32; off > 0; off >>= 1) {
            s   += __shfl_down(s, off);
            cnt += __shfl_down(cnt, off);
        }
        __shared__ float ws[4][2];
        const int wave = tid >> 6, lane = tid & 63;
        if (lane == 0) { ws[wave][0] = s; ws[wave][1] = cnt; }
        __syncthreads();
        if (tid == 0) {
            partial[2 * bid]     = ws[0][0] + ws[1][0] + ws[2][0] + ws[3][0];
            partial[2 * bid + 1] = ws[0][1] + ws[1][1] + ws[2][1] + ws[3][1];
        }
    } else {
        // sum(G) = sum over r in {0,1,H-2,H-1} x c in {0,1,W-2,W-1} of
        // wr*wc*B(r,c); w=-1 at {0,1}, +1 at {n-2,n-1}; B = 3x3 gauss of t-p.
        const float* pr = (const float*)pred;
        const float* tg = (const float*)target;
        float y = 0.f;
        if (tid < 16) {
            const int rows[4] = {0, 1, H - 2, H - 1};
            const int cols[4] = {0, 1, W - 2, W - 1};
            const float g[3] = {0.25f, 0.5f, 0.25f};
            const int ri = tid >> 2, ci = tid & 3;
            const int r = rows[ri], c = cols[ci];
            float b = 0.f;
            #pragma unroll
            for (int a = -1; a <= 1; ++a) {
                #pragma unroll
                for (int e = -1; e <= 1; ++e) {
                    int rr = reflect_idx(r + a, H);
                    int cc = reflect_idx(c + e, W);
                    b += g[a + 1] * g[e + 1] * (tg[rr * W + cc] - pr[rr * W + cc]);
                }
            }
            y = (((ri < 2) ? -1.f : 1.f) * ((ci < 2) ? -1.f : 1.f)) * b;
        }
        #pragma unroll
        for (int off = 8; off > 0; off >>= 1) y += __shfl_down(y, off);
        if (tid == 0) partial[2 * NBLK] = y;
    }
}

// One block: reduce NBLK (s,cnt) float2 partials + corner y -> scalar loss.
__global__ __launch_bounds__(256)
void finalize(const float* __restrict__ partial, float* __restrict__ out) {
    const int tid = threadIdx.x;
    const float2* p2 = (const float2*)partial;
    double s = 0.0, c = 0.0;
    #pragma unroll
    for (int j = 0; j < NBLK / 256; ++j) {
        float2 v = p2[tid + j * 256];
        s += (double)v.x;
        c += (double)v.y;
    }
    #pragma unroll
    for (int off = 32; off > 0; off >>= 1) {
        s += __shfl_down(s, off);
        c += __shfl_down(c, off);
    }
    __shared__ double ws[4][2];
    const int wave = tid >> 6, lane = tid & 63;
    if (lane == 0) { ws[wave][0] = s; ws[wave][1] = c; }
    __syncthreads();
    if (tid == 0) {
        double sd2 = ws[0][0] + ws[1][0] + ws[2][0] + ws[3][0];
        double cnt = ws[0][1] + ws[1][1] + ws[2][1] + ws[3][1];
        double mse = sd2 / fmax(cnt, 1.0);
        double meanG = (double)partial[2 * NBLK] / ((double)H * (double)W);
        out[0] = (float)(ALPHA * meanG + (1.0 - ALPHA) * mse);
    }
}

extern "C" void kernel_launch(void* const* d_in, const int* in_sizes, int n_in,
                              void* d_out, int out_size, void* d_ws, size_t ws_size,
                              hipStream_t stream) {
    const float* pred   = (const float*)d_in[0];
    const float* target = (const float*)d_in[1];
    float* out = (float*)d_out;
    float* partial = (float*)d_ws;   // (2*NBLK + 1) floats, all written every call

    mse_kernel<<<NBLK + 1, 256, 0, stream>>>((const f4*)pred,
                                             (const f4*)target, partial);
    finalize<<<1, 256, 0, stream>>>(partial, out);
}